// Round 3
// baseline (398.028 us; speedup 1.0000x reference)
//
#include <hip/hip_runtime.h>
#include <math.h>

// ---- problem constants ----
#define NE   1024
#define ROWS 16384
#define BM   64
#define NBLK 256
#define SQ8F 2.8284271247461903f   // float32(math.sqrt(8)), as numpy casts it

// ---- workspace layout (bytes) ----
#define WC_OFF   0u          // Wc: 1024*192 f32 = 786432
#define BC_OFF   786432u     // bc: 192 f32      = 768
#define QP_OFF   787200u     // qPg: 16384*16 f32 = 1048576
#define KP_OFF   1835776u    // kPg: 16384*16 f32 = 1048576
#define SP_OFF   2884352u    // Spart: 256*1024 f32 = 1048576
#define S_OFF    3932928u    // S: 4*16*64 f32 = 16384
#define KS_OFF   3949312u    // kSumF: 64 f32 = 256
// total ~3.95 MB

// ---------------- K0: pack Wc = [Wq | Wk | Wv] (pure copy, no arithmetic)
__global__ __launch_bounds__(256) void k0_pack(
    const float* __restrict__ Wq, const float* __restrict__ bq,
    const float* __restrict__ Wk, const float* __restrict__ bk,
    const float* __restrict__ Wv, const float* __restrict__ bv,
    float* __restrict__ Wc, float* __restrict__ bc)
{
    int g = blockIdx.x * 256 + threadIdx.x;
    if (g < 1024) {
        #pragma unroll 4
        for (int j = 0; j < 64; ++j) {
            Wc[g*192 + j]       = Wq[g*64 + j];
            Wc[g*192 + 64 + j]  = Wk[g*64 + j];
            Wc[g*192 + 128 + j] = Wv[g*64 + j];
        }
    } else if (g < 1024 + 192) {
        int j = g - 1024;
        bc[j] = (j < 64) ? bq[j] : (j < 128 ? bk[j - 64] : bv[j - 128]);
    }
}

// ---------------- K1: 192-col f32 GEMM (sequential-k chains, BLAS-like) +
// f32 p-chains + features + S partials. Block = 64 rows, 4 waves, 48 cols/wave.
__global__ __launch_bounds__(256) void k1_main(
    const float* __restrict__ x, const float* __restrict__ Wc,
    const float* __restrict__ bc, const float* __restrict__ w,
    float* __restrict__ qPg, float* __restrict__ kPg,
    float* __restrict__ Spart)
{
    __shared__ union U {
        float xsT[64][65];     // x chunk transposed [k][row]
        float vals[64][193];   // q(0:64) | k(64:128) | v(128:192), biased
    } sm;
    __shared__ float kp_lds[64][17];

    const int t    = threadIdx.x;
    const int lane = t & 63;
    const int wv   = __builtin_amdgcn_readfirstlane(t >> 6);
    const int row0 = blockIdx.x * BM;
    const int row  = row0 + lane;

    float acc[48];
    #pragma unroll
    for (int j = 0; j < 48; ++j) acc[j] = 0.f;

    const int tr = t >> 4;   // 0..15
    const int c4 = t & 15;   // 0..15

    float4 f4[4];
    #pragma unroll
    for (int p = 0; p < 4; ++p)
        f4[p] = ((const float4*)(x + (size_t)(row0 + p*16 + tr) * NE))[c4];

    for (int c = 0; c < 16; ++c) {
        __syncthreads();
        #pragma unroll
        for (int p = 0; p < 4; ++p) {
            sm.xsT[c4*4 + 0][p*16 + tr] = f4[p].x;
            sm.xsT[c4*4 + 1][p*16 + tr] = f4[p].y;
            sm.xsT[c4*4 + 2][p*16 + tr] = f4[p].z;
            sm.xsT[c4*4 + 3][p*16 + tr] = f4[p].w;
        }
        __syncthreads();
        if (c < 15) {
            #pragma unroll
            for (int p = 0; p < 4; ++p)
                f4[p] = ((const float4*)(x + (size_t)(row0 + p*16 + tr) * NE + (size_t)(c+1)*64))[c4];
        }
        const float* Wb = Wc + (size_t)(c*64)*192 + wv*48;   // wave-uniform
        for (int kk = 0; kk < 64; kk += 2) {
            float xa0 = sm.xsT[kk][lane];
            float xa1 = sm.xsT[kk + 1][lane];
            const float* w0 = Wb + (size_t)kk * 192;
            const float* w1 = w0 + 192;
            #pragma unroll
            for (int j = 0; j < 48; ++j) acc[j] = fmaf(xa0, w0[j], acc[j]);
            #pragma unroll
            for (int j = 0; j < 48; ++j) acc[j] = fmaf(xa1, w1[j], acc[j]);
        }
    }

    __syncthreads();   // done with xsT; switch union to vals
    {
        const float* bcv = bc + wv*48;
        #pragma unroll
        for (int j = 0; j < 48; ++j)
            sm.vals[lane][wv*48 + j] = acc[j] + bcv[j];   // np: matmul then +bias
    }
    __syncthreads();

    // ---- features: p = q@w (sequential d-chain, f32), then sincos/√8 ----
    {
        const int g = wv;   // this wave computes p-cols 2g, 2g+1 for q and k
        float pq0 = 0.f, pq1 = 0.f, pk0 = 0.f, pk1 = 0.f;
        for (int d = 0; d < 64; ++d) {
            float qd = sm.vals[lane][d];
            float kd = sm.vals[lane][64 + d];
            float w0 = w[d*8 + 2*g];       // wave-uniform -> scalar loads
            float w1 = w[d*8 + 2*g + 1];
            pq0 = fmaf(qd, w0, pq0);
            pq1 = fmaf(qd, w1, pq1);
            pk0 = fmaf(kd, w0, pk0);
            pk1 = fmaf(kd, w1, pk1);
        }
        double s, c;
        float qc0, qc1, qs0, qs1, kc0, kc1, ks0, ks1;
        sincos((double)pq0, &s, &c); qc0 = (float)c / SQ8F; qs0 = (float)s / SQ8F;
        sincos((double)pq1, &s, &c); qc1 = (float)c / SQ8F; qs1 = (float)s / SQ8F;
        sincos((double)pk0, &s, &c); kc0 = (float)c / SQ8F; ks0 = (float)s / SQ8F;
        sincos((double)pk1, &s, &c); kc1 = (float)c / SQ8F; ks1 = (float)s / SQ8F;

        float* qp = qPg + (size_t)row * 16;
        qp[2*g]     = qc0; qp[2*g + 1]     = qc1;
        qp[8 + 2*g] = qs0; qp[8 + 2*g + 1] = qs1;
        float* kp = kPg + (size_t)row * 16;
        kp[2*g]     = kc0; kp[2*g + 1]     = kc1;
        kp[8 + 2*g] = ks0; kp[8 + 2*g + 1] = ks1;
        kp_lds[lane][2*g]     = kc0; kp_lds[lane][2*g + 1]     = kc1;
        kp_lds[lane][8 + 2*g] = ks0; kp_lds[lane][8 + 2*g + 1] = ks1;
    }
    __syncthreads();

    // ---- S partial (precision non-critical) ----
    {
        const int m  = t >> 4;
        const int d4 = (t & 15) * 4;
        float a0 = 0.f, a1 = 0.f, a2 = 0.f, a3 = 0.f;
        #pragma unroll 8
        for (int r = 0; r < 64; ++r) {
            float kp = kp_lds[r][m];
            const float* vv = &sm.vals[r][128 + d4];
            a0 = fmaf(kp, vv[0], a0);
            a1 = fmaf(kp, vv[1], a1);
            a2 = fmaf(kp, vv[2], a2);
            a3 = fmaf(kp, vv[3], a3);
        }
        float4* sp = (float4*)(Spart + (size_t)blockIdx.x * 1024 + m*64 + d4);
        sp[0] = make_float4(a0, a1, a2, a3);
    }
}

// ---------------- K2: reduce S partials (f32 sequential; S precision non-critical)
__global__ __launch_bounds__(256) void k2_reduce(
    const float* __restrict__ Spart, float* __restrict__ S)
{
    int g = blockIdx.x * 256 + threadIdx.x;   // 0..4095
    int b = g >> 10, e = g & 1023;
    float s = 0.f;
    for (int i = 0; i < 64; ++i) s += Spart[(size_t)(b*64 + i) * 1024 + e];
    S[g] = s;
}

// ---------------- K2b: kSum = flat SEQUENTIAL f32 chain over t (numpy outer-axis reduce)
__global__ __launch_bounds__(64) void k2b_ksum(
    const float* __restrict__ kPg, float* __restrict__ kSumF)
{
    int t = threadIdx.x;          // 0..63 = (b,m)
    int b = t >> 4, m = t & 15;
    const float* base = kPg + (size_t)b * 4096 * 16 + m;
    float s = 0.f;
    for (int i = 0; i < 4096; ++i) s += base[(size_t)i * 16];
    kSumF[t] = s;
}

// ---------------- K3: D = sequential f32 mul+add (einsum-like), N f32, out = N/D (f32 div)
__global__ __launch_bounds__(256) void k3_out(
    const float* __restrict__ qPg, const float* __restrict__ S,
    const float* __restrict__ kSumF, float* __restrict__ out)
{
    __shared__ float S_lds[1024];
    __shared__ float ks[16];
    const int t = threadIdx.x;
    const int b = blockIdx.x >> 6;

    ((float4*)S_lds)[t] = ((const float4*)(S + (size_t)b * 1024))[t];
    if (t < 16) ks[t] = kSumF[b*16 + t];
    __syncthreads();

    const int row = blockIdx.x * BM + (t >> 2);
    const int c0  = (t & 3) * 16;
    const float4* qp = (const float4*)(qPg + (size_t)row * 16);
    float4 q0 = qp[0], q1 = qp[1], q2 = qp[2], q3 = qp[3];
    float q[16] = { q0.x,q0.y,q0.z,q0.w, q1.x,q1.y,q1.z,q1.w,
                    q2.x,q2.y,q2.z,q2.w, q3.x,q3.y,q3.z,q3.w };

    float D = 0.f;
    #pragma unroll
    for (int m = 0; m < 16; ++m)
        D = __fadd_rn(D, __fmul_rn(q[m], ks[m]));   // no FMA: mirror einsum

    float a[16];
    #pragma unroll
    for (int j = 0; j < 16; ++j) a[j] = 0.f;
    #pragma unroll
    for (int m = 0; m < 16; ++m) {
        const float qm = q[m];
        const float* sr = S_lds + m*64 + c0;
        #pragma unroll
        for (int j = 0; j < 16; ++j) a[j] = fmaf(qm, sr[j], a[j]);
    }

    float r[16];
    #pragma unroll
    for (int j = 0; j < 16; ++j) r[j] = a[j] / D;   // f32 division like np N/D

    float4* op = (float4*)(out + (size_t)row * 64 + c0);
    op[0] = make_float4(r[0],  r[1],  r[2],  r[3]);
    op[1] = make_float4(r[4],  r[5],  r[6],  r[7]);
    op[2] = make_float4(r[8],  r[9],  r[10], r[11]);
    op[3] = make_float4(r[12], r[13], r[14], r[15]);
}

extern "C" void kernel_launch(void* const* d_in, const int* in_sizes, int n_in,
                              void* d_out, int out_size, void* d_ws, size_t ws_size,
                              hipStream_t stream)
{
    const float* x  = (const float*)d_in[0];
    const float* Wq = (const float*)d_in[1];
    const float* bq = (const float*)d_in[2];
    const float* Wk = (const float*)d_in[3];
    const float* bk = (const float*)d_in[4];
    const float* Wv = (const float*)d_in[5];
    const float* bv = (const float*)d_in[6];
    const float* w  = (const float*)d_in[7];

    char* ws = (char*)d_ws;
    float* Wc    = (float*)(ws + WC_OFF);
    float* bc    = (float*)(ws + BC_OFF);
    float* qPg   = (float*)(ws + QP_OFF);
    float* kPg   = (float*)(ws + KP_OFF);
    float* Spart = (float*)(ws + SP_OFF);
    float* S     = (float*)(ws + S_OFF);
    float* kSumF = (float*)(ws + KS_OFF);
    float* out   = (float*)d_out;

    hipLaunchKernelGGL(k0_pack,  dim3(5),    dim3(256), 0, stream,
                       Wq, bq, Wk, bk, Wv, bv, Wc, bc);
    hipLaunchKernelGGL(k1_main,  dim3(NBLK), dim3(256), 0, stream,
                       x, Wc, bc, w, qPg, kPg, Spart);
    hipLaunchKernelGGL(k2_reduce, dim3(16),  dim3(256), 0, stream,
                       Spart, S);
    hipLaunchKernelGGL(k2b_ksum, dim3(1),    dim3(64),  0, stream,
                       kPg, kSumF);
    hipLaunchKernelGGL(k3_out,   dim3(NBLK), dim3(256), 0, stream,
                       qPg, S, kSumF, out);
}

// Round 4
// 194.153 us; speedup vs baseline: 2.0501x; 2.0501x over previous
//
#include <hip/hip_runtime.h>
#include <math.h>

// ---- problem constants ----
#define NE   1024
#define ROWS 16384
#define BM   64
#define NBLK 256
#define SQ8F 2.8284271247461903f   // float32(math.sqrt(8)) as numpy casts it

// ---- workspace layout (bytes) ----
#define WC_OFF   0u          // Wc: 1024*192 f32 = 786432
#define BC_OFF   786432u     // bc: 192 f32      = 768
#define QP_OFF   787200u     // qPg: 16384*16 f32 = 1048576
#define KPT_OFF  1835776u    // kPgT: 64*4096 f32 = 1048576  ([b*16+m][t])
#define SP_OFF   2884352u    // Spart: 256*1024 f32 = 1048576
#define S_OFF    3932928u    // S: 4*16*64 f32 = 16384
#define KS_OFF   3949312u    // kSumF: 64 f32 = 256
// total ~3.95 MB

// ---------------- K0: pack Wc = [Wq | Wk | Wv] (pure copy, float4)
__global__ __launch_bounds__(256) void k0_pack(
    const float* __restrict__ Wq, const float* __restrict__ bq,
    const float* __restrict__ Wk, const float* __restrict__ bk,
    const float* __restrict__ Wv, const float* __restrict__ bv,
    float* __restrict__ Wc, float* __restrict__ bc)
{
    int idx = blockIdx.x * 256 + threadIdx.x;
    if (idx < 49152) {                      // 1024 rows * 48 float4
        int row = idx / 48;
        int q4  = idx - row * 48;
        float4 v;
        if (q4 < 16)      v = ((const float4*)Wq)[row * 16 + q4];
        else if (q4 < 32) v = ((const float4*)Wk)[row * 16 + (q4 - 16)];
        else              v = ((const float4*)Wv)[row * 16 + (q4 - 32)];
        ((float4*)Wc)[(size_t)row * 48 + q4] = v;
    } else if (idx < 49152 + 192) {
        int j = idx - 49152;
        bc[j] = (j < 64) ? bq[j] : (j < 128 ? bk[j - 64] : bv[j - 128]);
    }
}

// ---------------- K1: 192-col f32 GEMM + features + S partials.
// 1024 threads = 16 waves; wave wv: cols wv*12..wv*12+11 (wave-uniform -> s_load W),
// thread: row = lane, 12 cols, sequential-k chain (bit-identical to round-3).
__global__ __launch_bounds__(1024, 4) void k1_main(
    const float* __restrict__ x, const float* __restrict__ Wc,
    const float* __restrict__ bc, const float* __restrict__ w,
    float* __restrict__ qPg, float* __restrict__ kPgT,
    float* __restrict__ Spart)
{
    __shared__ union U {
        float xs[2][64][68];   // x chunk, row-major, double-buffered (b128-friendly)
        float vals[64][196];   // q(0:64) | k(64:128) | v(128:192), biased
    } sm;
    __shared__ float kp_lds[64][17];

    const int t    = threadIdx.x;
    const int lane = t & 63;
    const int wv   = __builtin_amdgcn_readfirstlane(t >> 6);   // 0..15
    const int row0 = blockIdx.x * BM;

    float acc[12];
    #pragma unroll
    for (int j = 0; j < 12; ++j) acc[j] = 0.f;

    const int srow = t >> 4;    // 0..63
    const int sc4  = t & 15;    // 0..15
    const float* gsrc = x + (size_t)(row0 + srow) * NE + sc4 * 4;

    float4 pf = *(const float4*)gsrc;
    *(float4*)&sm.xs[0][srow][sc4 * 4] = pf;
    __syncthreads();

    for (int c = 0; c < 16; ++c) {
        if (c < 15) pf = *(const float4*)(gsrc + (size_t)(c + 1) * 64);
        const float* Wb = Wc + (size_t)(c * 64) * 192 + wv * 12;   // wave-uniform
        const float (*xsb)[68] = sm.xs[c & 1];
        #pragma unroll 2
        for (int kq = 0; kq < 16; ++kq) {
            float4 xa = *(const float4*)&xsb[lane][kq * 4];
            const float* w0 = Wb + (size_t)(kq * 4) * 192;
            #pragma unroll
            for (int j = 0; j < 12; ++j) acc[j] = fmaf(xa.x, w0[j],       acc[j]);
            #pragma unroll
            for (int j = 0; j < 12; ++j) acc[j] = fmaf(xa.y, w0[192 + j], acc[j]);
            #pragma unroll
            for (int j = 0; j < 12; ++j) acc[j] = fmaf(xa.z, w0[384 + j], acc[j]);
            #pragma unroll
            for (int j = 0; j < 12; ++j) acc[j] = fmaf(xa.w, w0[576 + j], acc[j]);
        }
        if (c < 15) *(float4*)&sm.xs[(c + 1) & 1][srow][sc4 * 4] = pf;
        __syncthreads();
    }

    // ---- epilogue: write biased q|k|v to LDS (union switch: all xs reads done) ----
    {
        const float* bcv = bc + wv * 12;
        #pragma unroll
        for (int j = 0; j < 12; ++j)
            sm.vals[lane][wv * 12 + j] = acc[j] + bcv[j];   // np: matmul then +bias
    }
    __syncthreads();

    // ---- features: 1024 threads = 64 rows x 8 pcols x {q,k}; sequential d-chain ----
    {
        const int frow = t >> 4;
        const int sub  = t & 15;
        const int pcol = sub & 7;
        const int isk  = sub >> 3;
        const float* vrow = &sm.vals[frow][isk * 64];
        float p = 0.f;
        for (int d = 0; d < 64; ++d)
            p = fmaf(vrow[d], w[d * 8 + pcol], p);
        double sd, cd;
        sincos((double)p, &sd, &cd);
        const float cf = (float)cd / SQ8F;
        const float sf = (float)sd / SQ8F;
        const int grow = row0 + frow;
        if (isk == 0) {
            qPg[(size_t)grow * 16 + pcol]     = cf;
            qPg[(size_t)grow * 16 + 8 + pcol] = sf;
        } else {
            const int b  = grow >> 12;          // batch
            const int tt = grow & 4095;         // t within batch
            kPgT[(size_t)(b * 16 + pcol)     * 4096 + tt] = cf;
            kPgT[(size_t)(b * 16 + 8 + pcol) * 4096 + tt] = sf;
            kp_lds[frow][pcol]     = cf;
            kp_lds[frow][8 + pcol] = sf;
        }
    }
    __syncthreads();

    // ---- S partial: wave wv = feature m, lane = d; chain over 64 rows ----
    {
        const int m = wv;
        const int d = lane;
        float a = 0.f;
        #pragma unroll 8
        for (int r = 0; r < 64; ++r)
            a = fmaf(kp_lds[r][m], sm.vals[r][128 + d], a);
        Spart[(size_t)blockIdx.x * 1024 + m * 64 + d] = a;
    }
}

// ---------------- K2: blocks 0..15 reduce S partials; block 16 = kSum chains
__global__ __launch_bounds__(256) void k2_reduce(
    const float* __restrict__ Spart, float* __restrict__ S,
    const float* __restrict__ kPgT, float* __restrict__ kSumF)
{
    if (blockIdx.x < 16) {
        int g = blockIdx.x * 256 + threadIdx.x;   // 0..4095
        int b = g >> 10, e = g & 1023;
        float s = 0.f;
        for (int i = 0; i < 64; ++i) s += Spart[(size_t)(b * 64 + i) * 1024 + e];
        S[g] = s;
    } else if (threadIdx.x < 64) {
        // kSum: flat SEQUENTIAL f32 chain over t (matches numpy outer-axis reduce)
        int t = threadIdx.x;                       // (b,m)
        const float4* p4 = (const float4*)(kPgT + (size_t)t * 4096);
        float s = 0.f;
        for (int i = 0; i < 1024; ++i) {
            float4 v = p4[i];
            s += v.x; s += v.y; s += v.z; s += v.w;   // same chain order
        }
        kSumF[t] = s;
    }
}

// ---------------- K3: D = sequential f32 mul+add, N f32 fma, out = N/D
__global__ __launch_bounds__(256) void k3_out(
    const float* __restrict__ qPg, const float* __restrict__ S,
    const float* __restrict__ kSumF, float* __restrict__ out)
{
    __shared__ float S_lds[1024];
    __shared__ float ks[16];
    const int t = threadIdx.x;
    const int b = blockIdx.x >> 6;

    ((float4*)S_lds)[t] = ((const float4*)(S + (size_t)b * 1024))[t];
    if (t < 16) ks[t] = kSumF[b * 16 + t];
    __syncthreads();

    const int row = blockIdx.x * BM + (t >> 2);
    const int c0  = (t & 3) * 16;
    const float4* qp = (const float4*)(qPg + (size_t)row * 16);
    float4 q0 = qp[0], q1 = qp[1], q2 = qp[2], q3 = qp[3];
    float q[16] = { q0.x,q0.y,q0.z,q0.w, q1.x,q1.y,q1.z,q1.w,
                    q2.x,q2.y,q2.z,q2.w, q3.x,q3.y,q3.z,q3.w };

    float D = 0.f;
    #pragma unroll
    for (int m = 0; m < 16; ++m)
        D = __fadd_rn(D, __fmul_rn(q[m], ks[m]));   // no FMA: mirror einsum

    float a[16];
    #pragma unroll
    for (int j = 0; j < 16; ++j) a[j] = 0.f;
    #pragma unroll
    for (int m = 0; m < 16; ++m) {
        const float qm = q[m];
        const float* sr = S_lds + m * 64 + c0;
        #pragma unroll
        for (int j = 0; j < 16; ++j) a[j] = fmaf(qm, sr[j], a[j]);
    }

    float r[16];
    #pragma unroll
    for (int j = 0; j < 16; ++j) r[j] = a[j] / D;

    float4* op = (float4*)(out + (size_t)row * 64 + c0);
    op[0] = make_float4(r[0],  r[1],  r[2],  r[3]);
    op[1] = make_float4(r[4],  r[5],  r[6],  r[7]);
    op[2] = make_float4(r[8],  r[9],  r[10], r[11]);
    op[3] = make_float4(r[12], r[13], r[14], r[15]);
}

extern "C" void kernel_launch(void* const* d_in, const int* in_sizes, int n_in,
                              void* d_out, int out_size, void* d_ws, size_t ws_size,
                              hipStream_t stream)
{
    const float* x  = (const float*)d_in[0];
    const float* Wq = (const float*)d_in[1];
    const float* bq = (const float*)d_in[2];
    const float* Wk = (const float*)d_in[3];
    const float* bk = (const float*)d_in[4];
    const float* Wv = (const float*)d_in[5];
    const float* bv = (const float*)d_in[6];
    const float* w  = (const float*)d_in[7];

    char* ws = (char*)d_ws;
    float* Wc    = (float*)(ws + WC_OFF);
    float* bc    = (float*)(ws + BC_OFF);
    float* qPg   = (float*)(ws + QP_OFF);
    float* kPgT  = (float*)(ws + KPT_OFF);
    float* Spart = (float*)(ws + SP_OFF);
    float* S     = (float*)(ws + S_OFF);
    float* kSumF = (float*)(ws + KS_OFF);
    float* out   = (float*)d_out;

    hipLaunchKernelGGL(k0_pack,   dim3(193),  dim3(256),  0, stream,
                       Wq, bq, Wk, bk, Wv, bv, Wc, bc);
    hipLaunchKernelGGL(k1_main,   dim3(NBLK), dim3(1024), 0, stream,
                       x, Wc, bc, w, qPg, kPgT, Spart);
    hipLaunchKernelGGL(k2_reduce, dim3(17),   dim3(256),  0, stream,
                       Spart, S, kPgT, kSumF);
    hipLaunchKernelGGL(k3_out,    dim3(NBLK), dim3(256),  0, stream,
                       qPg, S, kSumF, out);
}